// Round 13
// baseline (57.469 us; speedup 1.0000x reference)
//
#include <hip/hip_runtime.h>
#include <hip/hip_bf16.h>
#include <math.h>

// DDRFMixer: out[b,t,d] = sum_n softmax_n(x[b,t,:]·W[n,:]) * x[b,t-off_n,d]
// x: [B,T,D] fp32, W: [7,D] fp32, out: [B,T,D] fp32
// B=4, T=4096, D=1024, offsets = {1,2,4,8,16,32,64}
//
// R12: FUSED LDS TAP-STAGING. Every x row is consumed 8x (1 xv + 7 taps by
// different output rows); R3..R11 all paid ~36 KB/row of register-load
// traffic through L1/L2. Here each block owns 64 consecutive rows:
//   Phase A: softmax weights for the 64 rows (R8's proven dot+DPP+softmax,
//            W held in VGPRs) -> 2 KB LDS array.
//   Phase B: 16 d-chunks of 64 floats; per chunk, stage [128 rows x 64 f]
//            (64 halo + 64 main) = 32 KB LDS tile with a reg-staged 1-ahead
//            pipeline (issue c+1 loads -> compute c from LDS -> barrier ->
//            ds_write -> barrier). Tap reads come from the LDS pipe
//            (2x L1 width, parallel to VMEM).
// VMEM drops to ~12 KB/row; taps (28 KB/row) move to LDS. Grid = 256 blocks
// = exactly 1 block/CU (8 waves). XCD-bijective swizzle keeps the halo
// partner (previous 64 rows) on the same XCD's L2.
// Causality: phase A zeroes masked weights; staged halo rows clamp to x[0]
// (only ever multiplied by zero weights). Batch boundaries via t = row%T.

#define N_TAPS 7
#define DIM 1024
#define T_LEN 4096
#define BLOCK_THREADS 512
#define G 64                 // output rows per block
#define H 64                 // halo rows (max offset)
#define SR (G + H)           // 128 staged rows
#define CH 64                // d-chunk width (floats)
#define NCH (DIM / CH)       // 16 chunks
#define RC4 (CH / 4)         // 16 float4 per staged row-chunk

// ---- DPP helpers: canonical GCN wave64 sum ----
template <int CTRL>
__device__ __forceinline__ float dpp_mov0(float v) {
    return __builtin_bit_cast(float,
        __builtin_amdgcn_update_dpp(0, __builtin_bit_cast(int, v),
                                    CTRL, 0xf, 0xf, true));
}
__device__ __forceinline__ float wave_sum_bcast(float v) {
    v += dpp_mov0<0x111>(v);   // row_shr:1
    v += dpp_mov0<0x112>(v);   // row_shr:2
    v += dpp_mov0<0x114>(v);   // row_shr:4
    v += dpp_mov0<0x118>(v);   // row_shr:8
    v += dpp_mov0<0x142>(v);   // row_bcast:15
    v += dpp_mov0<0x143>(v);   // row_bcast:31 -> lane63 = total
    return __builtin_bit_cast(float,
        __builtin_amdgcn_readlane(__builtin_bit_cast(int, v), 63));
}

__global__ __launch_bounds__(BLOCK_THREADS) void ddrf_mixer_kernel(
    const float* __restrict__ x,   // [B*T, D]
    const float* __restrict__ W,   // [N_TAPS, D]
    float* __restrict__ out,       // [B*T, D]
    int n_rows)
{
    constexpr int offs[N_TAPS] = {1, 2, 4, 8, 16, 32, 64};

    __shared__ float tile[SR * CH];     // 32 KB staged x tile
    __shared__ float wts[G][8];         // 2 KB weights

    // ---- bijective XCD swizzle (gridDim.x = 256, % 8 == 0) ----
    const int per = gridDim.x >> 3;
    const int wg  = (blockIdx.x & 7) * per + (blockIdx.x >> 3);
    const int gr0 = wg * G;

    const int wave = threadIdx.x >> 6;
    const int lane = threadIdx.x & 63;
    const int dofs = lane * 4;

    // ---- W resident in VGPRs for phase A (28 float4; freed after) ----
    float4 wreg[N_TAPS][4];
#pragma unroll
    for (int n = 0; n < N_TAPS; ++n)
#pragma unroll
        for (int k = 0; k < 4; ++k)
            wreg[n][k] =
                *reinterpret_cast<const float4*>(W + n * DIM + k * 256 + dofs);

    // ================= Phase A: weights for rows gr0 + wave*8 .. +7 =========
#pragma unroll 1
    for (int i = 0; i < 8; ++i) {
        const int lr  = wave * 8 + i;
        const int row = gr0 + lr;
        const int t   = row & (T_LEN - 1);
        const float* xrow = x + (size_t)row * DIM;

        float4 xv[4];
#pragma unroll
        for (int k = 0; k < 4; ++k)
            xv[k] = *reinterpret_cast<const float4*>(xrow + k * 256 + dofs);

        float p[N_TAPS];
#pragma unroll
        for (int n = 0; n < N_TAPS; ++n) {
            float s0 = fmaf(xv[0].x, wreg[n][0].x, fmaf(xv[0].y, wreg[n][0].y,
                       fmaf(xv[0].z, wreg[n][0].z, xv[0].w * wreg[n][0].w)));
            float s1 = fmaf(xv[1].x, wreg[n][1].x, fmaf(xv[1].y, wreg[n][1].y,
                       fmaf(xv[1].z, wreg[n][1].z, xv[1].w * wreg[n][1].w)));
            float s2 = fmaf(xv[2].x, wreg[n][2].x, fmaf(xv[2].y, wreg[n][2].y,
                       fmaf(xv[2].z, wreg[n][2].z, xv[2].w * wreg[n][2].w)));
            float s3 = fmaf(xv[3].x, wreg[n][3].x, fmaf(xv[3].y, wreg[n][3].y,
                       fmaf(xv[3].z, wreg[n][3].z, xv[3].w * wreg[n][3].w)));
            p[n] = (s0 + s1) + (s2 + s3);
        }

#pragma unroll
        for (int n = 0; n < N_TAPS; ++n)
            p[n] = wave_sum_bcast(p[n]);

        // softmax (no max subtraction; logits small) + causal mask
        float wn[N_TAPS];
        float wsum = 0.f;
#pragma unroll
        for (int n = 0; n < N_TAPS; ++n) {
            wn[n] = __expf(p[n]);
            wsum += wn[n];
        }
        const float inv = 1.0f / wsum;

        float v = 0.f;   // lane n (<7) holds weight n; lane 7 pad 0
#pragma unroll
        for (int n = 0; n < N_TAPS; ++n) {
            const float weff = wn[n] * inv * ((t >= offs[n]) ? 1.0f : 0.0f);
            v = (lane == n) ? weff : v;
        }
        if (lane < 8)
            wts[lr][lane] = v;
    }
    __syncthreads();   // weights ready

    // ================= Phase B: chunked LDS-staged mix =======================
    const int tid = threadIdx.x;

    // prologue: stage chunk 0
    {
        float4 sg[4];
#pragma unroll
        for (int s = 0; s < 4; ++s) {
            const int idx  = tid + s * BLOCK_THREADS;   // 0..2047
            const int srow = idx >> 4;                  // 0..127
            const int c4   = idx & 15;
            int g = gr0 - H + srow;
            g = (g < 0) ? 0 : g;                        // clamp: masked anyway
            sg[s] = *reinterpret_cast<const float4*>(
                x + (size_t)g * DIM + 0 * CH + c4 * 4);
        }
#pragma unroll
        for (int s = 0; s < 4; ++s) {
            const int idx = tid + s * BLOCK_THREADS;
            *reinterpret_cast<float4*>(&tile[idx * 4]) = sg[s];
        }
    }
    __syncthreads();   // tile[chunk 0] ready

#pragma unroll 1
    for (int c = 0; c < NCH; ++c) {
        // ---- issue chunk c+1 loads (latency hides under compute) ----
        float4 nxt[4];
        if (c + 1 < NCH) {
#pragma unroll
            for (int s = 0; s < 4; ++s) {
                const int idx  = tid + s * BLOCK_THREADS;
                const int srow = idx >> 4;
                const int c4   = idx & 15;
                int g = gr0 - H + srow;
                g = (g < 0) ? 0 : g;
                nxt[s] = *reinterpret_cast<const float4*>(
                    x + (size_t)g * DIM + (c + 1) * CH + c4 * 4);
            }
        }

        // ---- compute chunk c: lane -> (row group, col4); 2 passes ----
        const int c4 = lane & 15;            // 0..15 within 64-col chunk
#pragma unroll
        for (int j = 0; j < 2; ++j) {
            const int lr = wave * 8 + (lane >> 4) + j * 4;   // 0..63

            const float4 wA = *reinterpret_cast<const float4*>(&wts[lr][0]);
            const float4 wB = *reinterpret_cast<const float4*>(&wts[lr][4]);
            const float wv[N_TAPS] = { wA.x, wA.y, wA.z, wA.w,
                                       wB.x, wB.y, wB.z };

            float4 a = make_float4(0.f, 0.f, 0.f, 0.f);
#pragma unroll
            for (int n = 0; n < N_TAPS; ++n) {
                const float4 tv = *reinterpret_cast<const float4*>(
                    &tile[(lr + H - offs[n]) * CH + c4 * 4]);
                a.x = fmaf(wv[n], tv.x, a.x);
                a.y = fmaf(wv[n], tv.y, a.y);
                a.z = fmaf(wv[n], tv.z, a.z);
                a.w = fmaf(wv[n], tv.w, a.w);
            }
            *reinterpret_cast<float4*>(
                out + (size_t)(gr0 + lr) * DIM + c * CH + c4 * 4) = a;
        }

        __syncthreads();   // all reads of tile[chunk c] done
        if (c + 1 < NCH) {
#pragma unroll
            for (int s = 0; s < 4; ++s) {
                const int idx = tid + s * BLOCK_THREADS;
                *reinterpret_cast<float4*>(&tile[idx * 4]) = nxt[s];
            }
            __syncthreads();   // tile[chunk c+1] ready
        }
    }
}

extern "C" void kernel_launch(void* const* d_in, const int* in_sizes, int n_in,
                              void* d_out, int out_size, void* d_ws, size_t ws_size,
                              hipStream_t stream) {
    const float* x = (const float*)d_in[0];   // [B,T,D] fp32
    const float* W = (const float*)d_in[1];   // [N_TAPS,D] fp32
    float* out = (float*)d_out;               // [B,T,D] fp32

    const int n_rows   = in_sizes[0] / DIM;   // B*T = 16384
    const int n_blocks = n_rows / G;          // 256 (divisible by 8)

    ddrf_mixer_kernel<<<n_blocks, BLOCK_THREADS, 0, stream>>>(x, W, out, n_rows);
}

// Round 14
// 35.932 us; speedup vs baseline: 1.5994x; 1.5994x over previous
//
#include <hip/hip_runtime.h>
#include <hip/hip_bf16.h>
#include <math.h>

// DDRFMixer: out[b,t,d] = sum_n softmax_n(x[b,t,:]·W[n,:]) * x[b,t-off_n,d]
// x: [B,T,D] fp32, W: [7,D] fp32, out: [B,T,D] fp32
// B=4, T=4096, D=1024, offsets = {1,2,4,8,16,32,64}
//
// R13 = R8 (best: 34.4 us) with 1024-THREAD BLOCKS (16 waves, 16 rows/block):
//  - R8's limit is L1-return occupancy (~576 cy/row) needing ~32 resident
//    waves/CU to saturate; R8's 2048 short-lived 512-thr blocks averaged
//    only ~47% occupancy (dispatch churn + per-block W staging).
//  - 1024-thr blocks: thread cap gives 2 blocks/CU = 32 waves = 100%
//    theoretical occupancy; half the block churn; W staged once per 16 rows.
//  - Per-wave structure is UNCHANGED from R8 (every TLP-reducing variant
//    R9-R12 regressed; this is the pure more-TLP move).
// Kept: W in LDS, DPP wave reduce (VALU pipe), tap prefetch before the
// reduce (clamp+mask causality), no-max softmax, XCD-bijective swizzle,
// 1-ahead k-pipeline in combine, plain float4 stores.

#define N_TAPS 7
#define DIM 1024
#define T_LEN 4096
#define BLOCK_THREADS 1024
#define ROWS_PER_BLOCK 16    // one wave per row, 16 waves per block

// ---- DPP helpers: canonical GCN wave64 sum ----
template <int CTRL>
__device__ __forceinline__ float dpp_mov0(float v) {
    return __builtin_bit_cast(float,
        __builtin_amdgcn_update_dpp(0, __builtin_bit_cast(int, v),
                                    CTRL, 0xf, 0xf, true));
}
__device__ __forceinline__ float wave_sum_bcast(float v) {
    v += dpp_mov0<0x111>(v);   // row_shr:1
    v += dpp_mov0<0x112>(v);   // row_shr:2
    v += dpp_mov0<0x114>(v);   // row_shr:4
    v += dpp_mov0<0x118>(v);   // row_shr:8
    v += dpp_mov0<0x142>(v);   // row_bcast:15
    v += dpp_mov0<0x143>(v);   // row_bcast:31 -> lane63 = total
    return __builtin_bit_cast(float,
        __builtin_amdgcn_readlane(__builtin_bit_cast(int, v), 63));
}

__global__ __launch_bounds__(BLOCK_THREADS) void ddrf_mixer_kernel(
    const float* __restrict__ x,   // [B*T, D]
    const float* __restrict__ W,   // [N_TAPS, D]
    float* __restrict__ out,       // [B*T, D]
    int n_rows)
{
    constexpr int offs[N_TAPS] = {1, 2, 4, 8, 16, 32, 64};

    __shared__ float wlds[N_TAPS * DIM];   // 28 KB

    // ---- stage W into LDS (once per block) ----
    for (int i = threadIdx.x; i < N_TAPS * (DIM / 4); i += BLOCK_THREADS) {
        reinterpret_cast<float4*>(wlds)[i] =
            reinterpret_cast<const float4*>(W)[i];
    }
    __syncthreads();

    // ---- bijective XCD swizzle (gridDim.x = 1024, % 8 == 0) ----
    const int per = gridDim.x >> 3;
    const int wg  = (blockIdx.x & 7) * per + (blockIdx.x >> 3);

    const int wave = threadIdx.x >> 6;
    const int lane = threadIdx.x & 63;
    const int dofs = lane * 4;               // lane's base within each 256-chunk

    const int row = wg * ROWS_PER_BLOCK + wave;   // one wave per row
    if (row >= n_rows) return;
    const int t = row & (T_LEN - 1);
    const float* xrow = x + (size_t)row * DIM;

    // ---- this row's 16 elements (issue first; dots wait on these) ----
    float4 xv[4];
#pragma unroll
    for (int k = 0; k < 4; ++k)
        xv[k] = *reinterpret_cast<const float4*>(xrow + k * 256 + dofs);

    // ---- causal clamp + mask (branch-free => tap loads can issue now) ----
    const float* trow[N_TAPS];
    float tmask[N_TAPS];
#pragma unroll
    for (int n = 0; n < N_TAPS; ++n) {
        const bool ok = (t >= offs[n]);
        trow[n]  = xrow - (size_t)(ok ? offs[n] : 0) * DIM;
        tmask[n] = ok ? 1.0f : 0.0f;
    }

    // ---- prefetch k=0 taps: in flight across the reduce+softmax chain ----
    float4 tap[N_TAPS];
#pragma unroll
    for (int n = 0; n < N_TAPS; ++n)
        tap[n] = *reinterpret_cast<const float4*>(trow[n] + dofs);

    // ---- Phase 1: partial dots vs W (from LDS, parallel pipe) ----
    float p[N_TAPS];
#pragma unroll
    for (int n = 0; n < N_TAPS; ++n) {
        const float* wrow = &wlds[n * DIM];
        float4 w0 = *reinterpret_cast<const float4*>(wrow + 0 * 256 + dofs);
        float4 w1 = *reinterpret_cast<const float4*>(wrow + 1 * 256 + dofs);
        float4 w2 = *reinterpret_cast<const float4*>(wrow + 2 * 256 + dofs);
        float4 w3 = *reinterpret_cast<const float4*>(wrow + 3 * 256 + dofs);
        float s0 = fmaf(xv[0].x, w0.x, fmaf(xv[0].y, w0.y, fmaf(xv[0].z, w0.z, xv[0].w * w0.w)));
        float s1 = fmaf(xv[1].x, w1.x, fmaf(xv[1].y, w1.y, fmaf(xv[1].z, w1.z, xv[1].w * w1.w)));
        float s2 = fmaf(xv[2].x, w2.x, fmaf(xv[2].y, w2.y, fmaf(xv[2].z, w2.z, xv[2].w * w2.w)));
        float s3 = fmaf(xv[3].x, w3.x, fmaf(xv[3].y, w3.y, fmaf(xv[3].z, w3.z, xv[3].w * w3.w)));
        p[n] = (s0 + s1) + (s2 + s3);
    }

    // ---- DPP wave reduce (VALU pipe; 7 independent chains) ----
#pragma unroll
    for (int n = 0; n < N_TAPS; ++n)
        p[n] = wave_sum_bcast(p[n]);

    // ---- softmax over 7 taps, no max subtraction (|logit| small, exp-safe)
    //      + causal mask ----
    float wn[N_TAPS];
    float wsum = 0.f;
#pragma unroll
    for (int n = 0; n < N_TAPS; ++n) {
        wn[n] = __expf(p[n]);
        wsum += wn[n];
    }
    const float inv = 1.0f / wsum;
    float weff[N_TAPS];
#pragma unroll
    for (int n = 0; n < N_TAPS; ++n) weff[n] = wn[n] * inv * tmask[n];

    // ---- Phase 2: combine, 1-chunk-ahead pipeline over k ----
    float* orow = out + (size_t)row * DIM;
#pragma unroll
    for (int k = 0; k < 4; ++k) {
        float4 nxt[N_TAPS];
        if (k < 3) {
#pragma unroll
            for (int n = 0; n < N_TAPS; ++n)
                nxt[n] = *reinterpret_cast<const float4*>(
                    trow[n] + (k + 1) * 256 + dofs);
        }
        float4 a = make_float4(0.f, 0.f, 0.f, 0.f);
#pragma unroll
        for (int n = 0; n < N_TAPS; ++n) {
            a.x = fmaf(weff[n], tap[n].x, a.x);
            a.y = fmaf(weff[n], tap[n].y, a.y);
            a.z = fmaf(weff[n], tap[n].z, a.z);
            a.w = fmaf(weff[n], tap[n].w, a.w);
        }
        *reinterpret_cast<float4*>(orow + k * 256 + dofs) = a;
        if (k < 3) {
#pragma unroll
            for (int n = 0; n < N_TAPS; ++n) tap[n] = nxt[n];
        }
    }
}

extern "C" void kernel_launch(void* const* d_in, const int* in_sizes, int n_in,
                              void* d_out, int out_size, void* d_ws, size_t ws_size,
                              hipStream_t stream) {
    const float* x = (const float*)d_in[0];   // [B,T,D] fp32
    const float* W = (const float*)d_in[1];   // [N_TAPS,D] fp32
    float* out = (float*)d_out;               // [B,T,D] fp32

    const int n_rows   = in_sizes[0] / DIM;          // B*T = 16384
    const int n_blocks = n_rows / ROWS_PER_BLOCK;    // 1024 (divisible by 8)

    ddrf_mixer_kernel<<<n_blocks, BLOCK_THREADS, 0, stream>>>(x, W, out, n_rows);
}